// Round 14
// baseline (300.714 us; speedup 1.0000x reference)
//
#include <hip/hip_runtime.h>
#include <hip/hip_bf16.h>
#include <stdint.h>

typedef __bf16 bf16;
typedef __bf16 bf16x8 __attribute__((ext_vector_type(8)));
typedef __bf16 bf16x4v __attribute__((ext_vector_type(4)));
typedef float f32x4 __attribute__((ext_vector_type(4)));
typedef uint32_t u32;
typedef u32 u32x2 __attribute__((ext_vector_type(2)));

__device__ __forceinline__ void gld_lds16(const void* g, void* l) {
  __builtin_amdgcn_global_load_lds(
      (const __attribute__((address_space(1))) void*)g,
      (__attribute__((address_space(3))) void*)l, 16, 0, 0);
}

__device__ __forceinline__ f32x4 mfma16(bf16x8 a, bf16x8 b, f32x4 c) {
  return __builtin_amdgcn_mfma_f32_16x16x32_bf16(a, b, c, 0, 0, 0);
}

__device__ __forceinline__ u32 cvtpk_bf16(float lo, float hi) {
  u32 r;
  asm("v_cvt_pk_bf16_f32 %0, %1, %2" : "=v"(r) : "v"(lo), "v"(hi));
  return r;
}

__device__ __forceinline__ float fexp2(float x) {
#if __has_builtin(__builtin_amdgcn_exp2f)
  return __builtin_amdgcn_exp2f(x);
#else
  return exp2f(x);
#endif
}

// ---------------- fp32 -> bf16 elementwise convert ----------------
__global__ void cvt_bf16_k(const float* __restrict__ in, bf16* __restrict__ out, int n4) {
  int i = blockIdx.x * blockDim.x + threadIdx.x;
  if (i >= n4) return;
  f32x4 v = reinterpret_cast<const f32x4*>(in)[i];
  bf16x4v o;
  o[0] = (bf16)v[0]; o[1] = (bf16)v[1]; o[2] = (bf16)v[2]; o[3] = (bf16)v[3];
  reinterpret_cast<bf16x4v*>(out)[i] = o;
}

// ---------------- weight fp32 [K][N] -> bf16 transposed [N][K] ----------------
__global__ void wt_cvt_k(const float* __restrict__ W, bf16* __restrict__ WT) {
  __shared__ float t[32][33];
  int tx = threadIdx.x, ty = threadIdx.y;  // 32 x 8
  int bx = blockIdx.x * 32, by = blockIdx.y * 32;
#pragma unroll
  for (int j = 0; j < 32; j += 8)
    t[ty + j][tx] = W[(size_t)(by + ty + j) * 1024 + bx + tx];
  __syncthreads();
#pragma unroll
  for (int j = 0; j < 32; j += 8)
    WT[(size_t)(bx + ty + j) * 1024 + by + tx] = (bf16)t[tx][ty + j];
}

// ---------------- GEMM (verified) ----------------
// OUT_MODE 0: bf16 out [B,H,L,64] attention layout, (acc+bias)*scale
// OUT_MODE 1: fp32 out row-major [M][N]
// OUT_MODE 2: bf16 out TRANSPOSED attention layout VT[bh][dh][L]
template <int OUT_MODE>
__global__ __launch_bounds__(256, 2) void gemm_k(
    const bf16* __restrict__ A, const bf16* __restrict__ WT,
    const float* __restrict__ bias, void* __restrict__ Cout, float scale) {
  constexpr int K = 1024, N = 1024, BM = 128, BK = 64;
  constexpr int NT = K / BK;  // 16
  __shared__ char lds[2][2][BM * BK * 2];  // 64 KiB total
  const int lane = threadIdx.x & 63, w = threadIdx.x >> 6;
  const int nwg = gridDim.x;
  int bid = (int)blockIdx.x;
  bid = (bid & 7) * (nwg >> 3) + (bid >> 3);  // XCD swizzle (nwg % 8 == 0)
  const int bn = bid & 7;   // N/BN = 8
  const int bm = bid >> 3;
  const int wm = (w & 1) * 64, wn = (w >> 1) * 64;

  const char* gA = (const char*)(A + (size_t)bm * BM * K);
  const char* gB = (const char*)(WT + (size_t)bn * BM * K);

  auto stage = [&](int buf, int kt) {
    char* lA = lds[buf][0];
    char* lB = lds[buf][1];
#pragma unroll
    for (int i = 0; i < 4; ++i) {
      int row = w * 32 + i * 8 + (lane >> 3);
      size_t rb = (size_t)row * (K * 2) + (size_t)kt * (BK * 2) + (size_t)(lane & 7) * 16;
      gld_lds16(gA + rb, lA + (w * 32 + i * 8) * 128);
      gld_lds16(gB + rb, lB + (w * 32 + i * 8) * 128);
    }
  };

  f32x4 acc[4][4] = {};
  stage(0, 0);
  for (int kt = 0; kt < NT; ++kt) {
    __syncthreads();
    if (kt + 1 < NT) stage((kt + 1) & 1, kt + 1);
    const char* lA = lds[kt & 1][0];
    const char* lB = lds[kt & 1][1];
    bf16x8 af[4][2], bfr[4][2];
#pragma unroll
    for (int mi = 0; mi < 4; ++mi)
#pragma unroll
      for (int c = 0; c < 2; ++c) {
        int row = wm + mi * 16 + (lane & 15);
        int ch = c * 4 + (lane >> 4);
        af[mi][c] = *(const bf16x8*)(lA + row * 128 + ch * 16);
      }
#pragma unroll
    for (int ni = 0; ni < 4; ++ni)
#pragma unroll
      for (int c = 0; c < 2; ++c) {
        int row = wn + ni * 16 + (lane & 15);
        int ch = c * 4 + (lane >> 4);
        bfr[ni][c] = *(const bf16x8*)(lB + row * 128 + ch * 16);
      }
#pragma unroll
    for (int mi = 0; mi < 4; ++mi)
#pragma unroll
      for (int ni = 0; ni < 4; ++ni) {
        acc[mi][ni] = mfma16(af[mi][0], bfr[ni][0], acc[mi][ni]);
        acc[mi][ni] = mfma16(af[mi][1], bfr[ni][1], acc[mi][ni]);
      }
  }

#pragma unroll
  for (int ni = 0; ni < 4; ++ni) {
    int col = bn * 128 + wn + ni * 16 + (lane & 15);
    float bv = bias[col];
    if (OUT_MODE == 0) {
      bf16* out = (bf16*)Cout;
      int h = col >> 6, dh = col & 63;
#pragma unroll
      for (int mi = 0; mi < 4; ++mi)
#pragma unroll
        for (int r = 0; r < 4; ++r) {
          int row = bm * BM + wm + mi * 16 + (lane >> 4) * 4 + r;
          int b = row >> 11, li = row & 2047;
          out[(((size_t)(b * 16 + h) * 2048 + li) << 6) + dh] =
              (bf16)((acc[mi][ni][r] + bv) * scale);
        }
    } else if (OUT_MODE == 1) {
      float* out = (float*)Cout;
#pragma unroll
      for (int mi = 0; mi < 4; ++mi)
#pragma unroll
        for (int r = 0; r < 4; ++r) {
          int row = bm * BM + wm + mi * 16 + (lane >> 4) * 4 + r;
          out[(size_t)row * N + col] = acc[mi][ni][r] + bv;
        }
    } else {
      bf16* out = (bf16*)Cout;
      int h = col >> 6, dh = col & 63;
#pragma unroll
      for (int mi = 0; mi < 4; ++mi)
#pragma unroll
        for (int r = 0; r < 4; ++r) {
          int row = bm * BM + wm + mi * 16 + (lane >> 4) * 4 + r;
          int b = row >> 11, li = row & 2047;
          out[(((size_t)(b * 16 + h) * 64 + dh) << 11) + li] =
              (bf16)((acc[mi][ni][r] + bv) * scale);
        }
    }
  }
}

// ---------------- MFMA flash attention v6b: swapped QK^T + packed P-store (ordering fixed) ----
// r13 structure; fix: P stored through bf16-element vector type (TBAA-aliases the bf16x8
// read) AND explicit s_waitcnt lgkmcnt(0) + sched_barrier(0) between P write and read —
// rule 18: compiler waitcnt insertion is dependency-based; asm "memory" fences pin only
// program order, so a u32-typed store could race its bf16-typed read in HW.
__global__ __launch_bounds__(256, 4) void attn_mfma_k(
    const bf16* __restrict__ Q, const bf16* __restrict__ Kg,
    const bf16* __restrict__ VT, bf16* __restrict__ AO) {
  constexpr int L = 2048, DH = 64, NT = L / 64;
  __shared__ char ldsK[2][8192];    // K tiles  [64 keys][8 chunks x 16B], chunk-swizzled
  __shared__ char ldsVT[2][8192];   // VT tiles [64 dims][8 chunks x 16B], chunk-swizzled
  __shared__ char ldsP[4][2048];    // per-wave P [16 rows][8 chunks x 16B], chunk-swizzled
  const int lane = threadIdx.x & 63, w = threadIdx.x >> 6;
  const int nwg = gridDim.x;
  int bid = (int)blockIdx.x;
  bid = (bid & 7) * (nwg >> 3) + (bid >> 3);  // XCD swizzle (nwg = 1024, % 8 == 0)
  const int bh = bid >> 4;
  const int q0 = (bid & 15) * 128;
  const int b = bh >> 4, h = bh & 15;
  const int l7 = lane & 7;          // read-swizzle key (== row&7 for all fragment rows)
  const int q15 = lane & 15, g4 = lane >> 4;
  const int sl = lane >> 3;         // staging: row-within-chunk
  const int sw = l7 ^ sl;           // staging: inverse-swizzled source chunk

  // Q fragments (role: B operand now; same data/layout as before)
  const bf16* Qbase = Q + ((size_t)bh * L + q0 + w * 32) * DH;
  bf16x8 qf[2][2];
#pragma unroll
  for (int rt = 0; rt < 2; ++rt)
#pragma unroll
    for (int c = 0; c < 2; ++c)
      qf[rt][c] = *(const bf16x8*)(Qbase + (size_t)(rt * 16 + q15) * DH +
                                   (c * 4 + g4) * 8);

  const char* Kp  = (const char*)(Kg + (size_t)bh * L * DH);
  const char* VTp = (const char*)(VT + (size_t)bh * DH * L);

  auto stage = [&](int buf, int kt) {
#pragma unroll
    for (int c = 0; c < 2; ++c) {
      int chunk = w * 2 + c;  // 0..7, wave-uniform
      int row = chunk * 8 + sl;
      gld_lds16(Kp + (size_t)kt * 8192 + (size_t)row * 128 + sw * 16,
                ldsK[buf] + chunk * 1024);
      gld_lds16(VTp + (size_t)row * 4096 + (size_t)kt * 128 + sw * 16,
                ldsVT[buf] + chunk * 1024);
    }
  };

  f32x4 o[2][4] = {};
  float lpart[2] = {0.f, 0.f};   // per-lane: qrow=q15 (within tile rt), its g-quarter of keys

  stage(0, 0);
  for (int kt = 0; kt < NT; ++kt) {
    __syncthreads();  // drains prev stage (vmcnt=0) + protects buffer reuse
    if (kt + 1 < NT) stage((kt + 1) & 1, kt + 1);
    const char* lK  = ldsK[kt & 1];
    const char* lVT = ldsVT[kt & 1];

    // --- hoisted K fragments (8 x b128, conflict-free) ---
    bf16x8 kf[4][2];
#pragma unroll
    for (int sub = 0; sub < 4; ++sub)
#pragma unroll
      for (int c = 0; c < 2; ++c) {
        int key = sub * 16 + q15;
        int ch = (c * 4 + g4) ^ l7;
        kf[sub][c] = *(const bf16x8*)(lK + key * 128 + ch * 16);
      }

    bf16x8 pf[2][2];
#pragma unroll
    for (int rt = 0; rt < 2; ++rt) {
      // --- S^T = K Q^T (swapped operands; D: col=qrow, row=key) ---
      f32x4 s[4];
#pragma unroll
      for (int sub = 0; sub < 4; ++sub) {
        f32x4 acc = {};
        acc = mfma16(kf[sub][0], qf[rt][0], acc);
        acc = mfma16(kf[sub][1], qf[rt][1], acc);
        s[sub] = acc;
      }
      // --- p = exp2(s); pack adjacent keys; bf16-typed 8B stores (chunk-swizzled) ---
#pragma unroll
      for (int sub = 0; sub < 4; ++sub) {
        float p0 = fexp2(s[sub][0]), p1 = fexp2(s[sub][1]);
        float p2 = fexp2(s[sub][2]), p3 = fexp2(s[sub][3]);
        lpart[rt] += (p0 + p1) + (p2 + p3);
        u32x2 pw;
        pw[0] = cvtpk_bf16(p0, p1);
        pw[1] = cvtpk_bf16(p2, p3);
        bf16x4v pv = __builtin_bit_cast(bf16x4v, pw);  // bf16-elem type: aliases the read
        int chs = (2 * sub + (g4 >> 1)) ^ l7;  // key-bytes 32*sub+8*g4 -> chunk 2*sub+(g4>>1)
        *(bf16x4v*)(ldsP[w] + q15 * 128 + chs * 16 + (g4 & 1) * 8) = pv;
      }
      // HW-ordered P readback: drain LDS queue, then pin scheduler (rule 18)
      asm volatile("s_waitcnt lgkmcnt(0)" ::: "memory");
      __builtin_amdgcn_sched_barrier(0);
#pragma unroll
      for (int c = 0; c < 2; ++c) {
        int ch = (c * 4 + g4) ^ l7;
        pf[rt][c] = *(const bf16x8*)(ldsP[w] + q15 * 128 + ch * 16);
      }
      asm volatile("s_waitcnt lgkmcnt(0)" ::: "memory");
      __builtin_amdgcn_sched_barrier(0);  // reads complete before next rt's writes
    }

    // --- PV: hoisted VT fragments, 2 mfma per (n, rt) ---
#pragma unroll
    for (int n = 0; n < 4; ++n) {
      int dim = n * 16 + q15;
      bf16x8 vf[2];
#pragma unroll
      for (int c = 0; c < 2; ++c) {
        int ch = (c * 4 + g4) ^ l7;
        vf[c] = *(const bf16x8*)(lVT + dim * 128 + ch * 16);
      }
#pragma unroll
      for (int rt = 0; rt < 2; ++rt) {
        o[rt][n] = mfma16(pf[rt][0], vf[0], o[rt][n]);
        o[rt][n] = mfma16(pf[rt][1], vf[1], o[rt][n]);
      }
    }
  }

  // --- final l: reduce over the 4 g-groups of each qrow (2 shfl rounds) ---
  float lf[2];
#pragma unroll
  for (int rt = 0; rt < 2; ++rt) {
    float v = lpart[rt];
    v += __shfl_xor(v, 16, 64);
    v += __shfl_xor(v, 32, 64);
    lf[rt] = v;  // all lanes: full l for qrow=q15 of tile rt
  }

  // --- epilogue: redistribute l to D-layout rows, write AO [B,L,1024] ---
#pragma unroll
  for (int rt = 0; rt < 2; ++rt) {
    float inv[4];
#pragma unroll
    for (int r = 0; r < 4; ++r)
      inv[r] = 1.f / __shfl(lf[rt], g4 * 4 + r, 64);  // src lane g4*4+r holds that qrow's l
#pragma unroll
    for (int n = 0; n < 4; ++n) {
      int col = h * 64 + n * 16 + q15;
#pragma unroll
      for (int r = 0; r < 4; ++r) {
        int qrow = q0 + w * 32 + rt * 16 + g4 * 4 + r;
        AO[((size_t)b * L + qrow) * 1024 + col] = (bf16)(o[rt][n][r] * inv[r]);
      }
    }
  }
}

// ---------------- launch ----------------
extern "C" void kernel_launch(void* const* d_in, const int* in_sizes, int n_in,
                              void* d_out, int out_size, void* d_ws, size_t ws_size,
                              hipStream_t stream) {
  (void)in_sizes; (void)n_in; (void)out_size;
  const size_t MB = 1u << 20;
  if (ws_size < 73 * MB) return;

  const float* q  = (const float*)d_in[0];
  const float* k  = (const float*)d_in[1];
  const float* v  = (const float*)d_in[2];
  const float* Wq = (const float*)d_in[3];
  const float* bq = (const float*)d_in[4];
  const float* Wk = (const float*)d_in[5];
  const float* bk = (const float*)d_in[6];
  const float* Wv = (const float*)d_in[7];
  const float* bv = (const float*)d_in[8];
  const float* Wo = (const float*)d_in[9];
  const float* bo = (const float*)d_in[10];

  char* ws = (char*)d_ws;
  bf16* qb  = (bf16*)(ws + 0 * MB);
  bf16* kb  = (bf16*)(ws + 16 * MB);
  bf16* vb  = (bf16*)(ws + 32 * MB);
  bf16* Qa  = (bf16*)(ws + 48 * MB);
  bf16* WqT = (bf16*)(ws + 64 * MB);
  bf16* WkT = (bf16*)(ws + 66 * MB);
  bf16* WvT = (bf16*)(ws + 68 * MB);
  bf16* WoT = (bf16*)(ws + 70 * MB);
  bf16* Ka = qb;   // reuse: qb dead after Q-proj
  bf16* VTa = kb;  // reuse: kb dead after K-proj (V-proj writes VT layout here)
  bf16* AO = vb;   // reuse: vb dead after V-proj

  dim3 tb(32, 8);
  wt_cvt_k<<<dim3(32, 32), tb, 0, stream>>>(Wq, WqT);
  wt_cvt_k<<<dim3(32, 32), tb, 0, stream>>>(Wk, WkT);
  wt_cvt_k<<<dim3(32, 32), tb, 0, stream>>>(Wv, WvT);
  wt_cvt_k<<<dim3(32, 32), tb, 0, stream>>>(Wo, WoT);

  const int n4 = (4 * 2048 * 1024) / 4;
  cvt_bf16_k<<<n4 / 256, 256, 0, stream>>>(q, qb, n4);
  cvt_bf16_k<<<n4 / 256, 256, 0, stream>>>(k, kb, n4);
  cvt_bf16_k<<<n4 / 256, 256, 0, stream>>>(v, vb, n4);

  // Q scale folds softmax 1/8 AND 1/ln2 (exp2-based softmax; shift/scale-exact)
  gemm_k<0><<<512, 256, 0, stream>>>(qb, WqT, bq, (void*)Qa, 0.125f * 1.4426950408889634f);
  gemm_k<0><<<512, 256, 0, stream>>>(kb, WkT, bk, (void*)Ka, 1.0f);
  gemm_k<2><<<512, 256, 0, stream>>>(vb, WvT, bv, (void*)VTa, 1.0f);

  attn_mfma_k<<<1024, 256, 0, stream>>>(Qa, Ka, VTa, AO);

  gemm_k<1><<<512, 256, 0, stream>>>(AO, WoT, bo, d_out, 1.0f);
}

// Round 17
// 215.919 us; speedup vs baseline: 1.3927x; 1.3927x over previous
//
#include <hip/hip_runtime.h>
#include <hip/hip_bf16.h>
#include <stdint.h>

typedef __bf16 bf16;
typedef __bf16 bf16x8 __attribute__((ext_vector_type(8)));
typedef __bf16 bf16x4v __attribute__((ext_vector_type(4)));
typedef float f32x4 __attribute__((ext_vector_type(4)));
typedef uint32_t u32;
typedef u32 u32x2 __attribute__((ext_vector_type(2)));

__device__ __forceinline__ void gld_lds16(const void* g, void* l) {
  __builtin_amdgcn_global_load_lds(
      (const __attribute__((address_space(1))) void*)g,
      (__attribute__((address_space(3))) void*)l, 16, 0, 0);
}

__device__ __forceinline__ f32x4 mfma16(bf16x8 a, bf16x8 b, f32x4 c) {
  return __builtin_amdgcn_mfma_f32_16x16x32_bf16(a, b, c, 0, 0, 0);
}

__device__ __forceinline__ u32 cvtpk_bf16(float lo, float hi) {
  u32 r;
  asm("v_cvt_pk_bf16_f32 %0, %1, %2" : "=v"(r) : "v"(lo), "v"(hi));
  return r;
}

__device__ __forceinline__ float fexp2(float x) {
#if __has_builtin(__builtin_amdgcn_exp2f)
  return __builtin_amdgcn_exp2f(x);
#else
  return exp2f(x);
#endif
}

// ---------------- fp32 -> bf16 elementwise convert: q,k,v fused ----------------
__global__ void cvt3_bf16_k(const float* __restrict__ q, const float* __restrict__ k,
                            const float* __restrict__ v, bf16* __restrict__ qb,
                            bf16* __restrict__ kb, bf16* __restrict__ vb, int n4) {
  int i = blockIdx.x * blockDim.x + threadIdx.x;
  if (i >= n4) return;
  const float* in = (blockIdx.y == 0) ? q : (blockIdx.y == 1) ? k : v;
  bf16* out = (blockIdx.y == 0) ? qb : (blockIdx.y == 1) ? kb : vb;
  f32x4 t = reinterpret_cast<const f32x4*>(in)[i];
  bf16x4v o;
  o[0] = (bf16)t[0]; o[1] = (bf16)t[1]; o[2] = (bf16)t[2]; o[3] = (bf16)t[3];
  reinterpret_cast<bf16x4v*>(out)[i] = o;
}

// ---------------- weight fp32 [K][N] -> bf16 transposed [N][K], 4 weights fused -------
__global__ void wt_cvt4_k(const float* __restrict__ W0, const float* __restrict__ W1,
                          const float* __restrict__ W2, const float* __restrict__ W3,
                          bf16* __restrict__ T0, bf16* __restrict__ T1,
                          bf16* __restrict__ T2, bf16* __restrict__ T3) {
  const float* W = (blockIdx.z == 0) ? W0 : (blockIdx.z == 1) ? W1
                  : (blockIdx.z == 2) ? W2 : W3;
  bf16* WT = (blockIdx.z == 0) ? T0 : (blockIdx.z == 1) ? T1
            : (blockIdx.z == 2) ? T2 : T3;
  __shared__ float t[32][33];
  int tx = threadIdx.x, ty = threadIdx.y;  // 32 x 8
  int bx = blockIdx.x * 32, by = blockIdx.y * 32;
#pragma unroll
  for (int j = 0; j < 32; j += 8)
    t[ty + j][tx] = W[(size_t)(by + ty + j) * 1024 + bx + tx];
  __syncthreads();
#pragma unroll
  for (int j = 0; j < 32; j += 8)
    WT[(size_t)(bx + ty + j) * 1024 + by + tx] = (bf16)t[tx][ty + j];
}

// ---------------- GEMM (verified) ----------------
// OUT_MODE 0: bf16 out [B,H,L,64] attention layout, (acc+bias)*scale
// OUT_MODE 1: fp32 out row-major [M][N]
// OUT_MODE 2: bf16 out TRANSPOSED attention layout VT[bh][dh][L]
template <int OUT_MODE>
__global__ __launch_bounds__(256, 2) void gemm_k(
    const bf16* __restrict__ A, const bf16* __restrict__ WT,
    const float* __restrict__ bias, void* __restrict__ Cout, float scale) {
  constexpr int K = 1024, N = 1024, BM = 128, BK = 64;
  constexpr int NT = K / BK;  // 16
  __shared__ char lds[2][2][BM * BK * 2];  // 64 KiB total
  const int lane = threadIdx.x & 63, w = threadIdx.x >> 6;
  const int nwg = gridDim.x;
  int bid = (int)blockIdx.x;
  bid = (bid & 7) * (nwg >> 3) + (bid >> 3);  // XCD swizzle (nwg % 8 == 0)
  const int bn = bid & 7;   // N/BN = 8
  const int bm = bid >> 3;
  const int wm = (w & 1) * 64, wn = (w >> 1) * 64;

  const char* gA = (const char*)(A + (size_t)bm * BM * K);
  const char* gB = (const char*)(WT + (size_t)bn * BM * K);

  auto stage = [&](int buf, int kt) {
    char* lA = lds[buf][0];
    char* lB = lds[buf][1];
#pragma unroll
    for (int i = 0; i < 4; ++i) {
      int row = w * 32 + i * 8 + (lane >> 3);
      size_t rb = (size_t)row * (K * 2) + (size_t)kt * (BK * 2) + (size_t)(lane & 7) * 16;
      gld_lds16(gA + rb, lA + (w * 32 + i * 8) * 128);
      gld_lds16(gB + rb, lB + (w * 32 + i * 8) * 128);
    }
  };

  f32x4 acc[4][4] = {};
  stage(0, 0);
  for (int kt = 0; kt < NT; ++kt) {
    __syncthreads();
    if (kt + 1 < NT) stage((kt + 1) & 1, kt + 1);
    const char* lA = lds[kt & 1][0];
    const char* lB = lds[kt & 1][1];
    bf16x8 af[4][2], bfr[4][2];
#pragma unroll
    for (int mi = 0; mi < 4; ++mi)
#pragma unroll
      for (int c = 0; c < 2; ++c) {
        int row = wm + mi * 16 + (lane & 15);
        int ch = c * 4 + (lane >> 4);
        af[mi][c] = *(const bf16x8*)(lA + row * 128 + ch * 16);
      }
#pragma unroll
    for (int ni = 0; ni < 4; ++ni)
#pragma unroll
      for (int c = 0; c < 2; ++c) {
        int row = wn + ni * 16 + (lane & 15);
        int ch = c * 4 + (lane >> 4);
        bfr[ni][c] = *(const bf16x8*)(lB + row * 128 + ch * 16);
      }
#pragma unroll
    for (int mi = 0; mi < 4; ++mi)
#pragma unroll
      for (int ni = 0; ni < 4; ++ni) {
        acc[mi][ni] = mfma16(af[mi][0], bfr[ni][0], acc[mi][ni]);
        acc[mi][ni] = mfma16(af[mi][1], bfr[ni][1], acc[mi][ni]);
      }
  }

#pragma unroll
  for (int ni = 0; ni < 4; ++ni) {
    int col = bn * 128 + wn + ni * 16 + (lane & 15);
    float bv = bias[col];
    if (OUT_MODE == 0) {
      bf16* out = (bf16*)Cout;
      int h = col >> 6, dh = col & 63;
#pragma unroll
      for (int mi = 0; mi < 4; ++mi)
#pragma unroll
        for (int r = 0; r < 4; ++r) {
          int row = bm * BM + wm + mi * 16 + (lane >> 4) * 4 + r;
          int b = row >> 11, li = row & 2047;
          out[(((size_t)(b * 16 + h) * 2048 + li) << 6) + dh] =
              (bf16)((acc[mi][ni][r] + bv) * scale);
        }
    } else if (OUT_MODE == 1) {
      float* out = (float*)Cout;
#pragma unroll
      for (int mi = 0; mi < 4; ++mi)
#pragma unroll
        for (int r = 0; r < 4; ++r) {
          int row = bm * BM + wm + mi * 16 + (lane >> 4) * 4 + r;
          out[(size_t)row * N + col] = acc[mi][ni][r] + bv;
        }
    } else {
      bf16* out = (bf16*)Cout;
      int h = col >> 6, dh = col & 63;
#pragma unroll
      for (int mi = 0; mi < 4; ++mi)
#pragma unroll
        for (int r = 0; r < 4; ++r) {
          int row = bm * BM + wm + mi * 16 + (lane >> 4) * 4 + r;
          int b = row >> 11, li = row & 2047;
          out[(((size_t)(b * 16 + h) * 64 + dh) << 11) + li] =
              (bf16)((acc[mi][ni][r] + bv) * scale);
        }
    }
  }
}

// ---------------- MFMA flash attention v7: packed P, per-rt buffers, 1 wait+SB per kt ----
// Evidence matrix: vector P stores REQUIRE hard lgkmcnt(0) + sched_barrier(0) before the
// readback (rule 18: hipcc hoists past inline-asm waits; r13/r15/r16 all raced without SB).
// Amortization: each rt gets its own P buffer -> ALL stores issue, then ONE wait+SB, then
// all reads. No WAR within kt (disjoint buffers); WAR across kt covered by the loop-top
// __syncthreads (compiler emits full lgkm/vm drain before s_barrier). lgkmcnt(0) is cheap
// here: global_load_lds prefetch counts in vmcnt, not lgkmcnt.
__global__ __launch_bounds__(256, 3) void attn_mfma_k(
    const bf16* __restrict__ Q, const bf16* __restrict__ Kg,
    const bf16* __restrict__ VT, bf16* __restrict__ AO) {
  constexpr int L = 2048, DH = 64, NT = L / 64;
  __shared__ char ldsK[2][8192];      // K tiles  [64 keys][8 chunks x 16B], chunk-swizzled
  __shared__ char ldsVT[2][8192];     // VT tiles [64 dims][8 chunks x 16B], chunk-swizzled
  __shared__ char ldsP[4][2][2048];   // per-wave, PER-RT P [16 rows][8 chunks x 16B]
  const int lane = threadIdx.x & 63, w = threadIdx.x >> 6;
  const int nwg = gridDim.x;
  int bid = (int)blockIdx.x;
  bid = (bid & 7) * (nwg >> 3) + (bid >> 3);  // XCD swizzle (nwg = 1024, % 8 == 0)
  const int bh = bid >> 4;
  const int q0 = (bid & 15) * 128;
  const int b = bh >> 4, h = bh & 15;
  const int l7 = lane & 7;          // read-swizzle key (== row&7 for all fragment rows)
  const int q15 = lane & 15, g4 = lane >> 4;
  const int sl = lane >> 3;         // staging: row-within-chunk
  const int sw = l7 ^ sl;           // staging: inverse-swizzled source chunk

  // Q fragments (role: B operand; GEMM A-frag pattern from global)
  const bf16* Qbase = Q + ((size_t)bh * L + q0 + w * 32) * DH;
  bf16x8 qf[2][2];
#pragma unroll
  for (int rt = 0; rt < 2; ++rt)
#pragma unroll
    for (int c = 0; c < 2; ++c)
      qf[rt][c] = *(const bf16x8*)(Qbase + (size_t)(rt * 16 + q15) * DH +
                                   (c * 4 + g4) * 8);

  const char* Kp  = (const char*)(Kg + (size_t)bh * L * DH);
  const char* VTp = (const char*)(VT + (size_t)bh * DH * L);

  auto stage = [&](int buf, int kt) {
#pragma unroll
    for (int c = 0; c < 2; ++c) {
      int chunk = w * 2 + c;  // 0..7, wave-uniform
      int row = chunk * 8 + sl;
      gld_lds16(Kp + (size_t)kt * 8192 + (size_t)row * 128 + sw * 16,
                ldsK[buf] + chunk * 1024);
      gld_lds16(VTp + (size_t)row * 4096 + (size_t)kt * 128 + sw * 16,
                ldsVT[buf] + chunk * 1024);
    }
  };

  f32x4 o[2][4] = {};
  float lpart[2] = {0.f, 0.f};   // per-lane: qrow=q15 (tile rt), its g-quarter of keys

  stage(0, 0);
  for (int kt = 0; kt < NT; ++kt) {
    __syncthreads();  // full drain (vm+lgkm) + buffer-reuse protection
    if (kt + 1 < NT) stage((kt + 1) & 1, kt + 1);
    const char* lK  = ldsK[kt & 1];
    const char* lVT = ldsVT[kt & 1];

    // --- hoisted K fragments (8 x b128, conflict-free) ---
    bf16x8 kf[4][2];
#pragma unroll
    for (int sub = 0; sub < 4; ++sub)
#pragma unroll
      for (int c = 0; c < 2; ++c) {
        int key = sub * 16 + q15;
        int ch = (c * 4 + g4) ^ l7;
        kf[sub][c] = *(const bf16x8*)(lK + key * 128 + ch * 16);
      }

    // --- phase 1: both row-tiles' S^T + exp2 + P stores (disjoint buffers) ---
#pragma unroll
    for (int rt = 0; rt < 2; ++rt) {
      f32x4 s[4];
#pragma unroll
      for (int sub = 0; sub < 4; ++sub) {
        f32x4 acc = {};
        acc = mfma16(kf[sub][0], qf[rt][0], acc);
        acc = mfma16(kf[sub][1], qf[rt][1], acc);
        s[sub] = acc;
      }
#pragma unroll
      for (int sub = 0; sub < 4; ++sub) {
        float p0 = fexp2(s[sub][0]), p1 = fexp2(s[sub][1]);
        float p2 = fexp2(s[sub][2]), p3 = fexp2(s[sub][3]);
        lpart[rt] += (p0 + p1) + (p2 + p3);
        u32x2 pw;
        pw[0] = cvtpk_bf16(p0, p1);
        pw[1] = cvtpk_bf16(p2, p3);
        bf16x4v pv = __builtin_bit_cast(bf16x4v, pw);
        int chs = (2 * sub + (g4 >> 1)) ^ l7;  // key-bytes 32*sub+8*g4 -> chunk 2*sub+(g4>>1)
        *(bf16x4v*)(ldsP[w][rt] + q15 * 128 + chs * 16 + (g4 & 1) * 8) = pv;
      }
    }

    // --- ONE ordering point per kt (r14-proven mechanism, rule 18) ---
    asm volatile("s_waitcnt lgkmcnt(0)" ::: "memory");
    __builtin_amdgcn_sched_barrier(0);

    // --- phase 2: P fragment readback (both rt) ---
    bf16x8 pf[2][2];
#pragma unroll
    for (int rt = 0; rt < 2; ++rt)
#pragma unroll
      for (int c = 0; c < 2; ++c) {
        int ch = (c * 4 + g4) ^ l7;
        pf[rt][c] = *(const bf16x8*)(ldsP[w][rt] + q15 * 128 + ch * 16);
      }

    // --- PV: hoisted VT fragments, 2 mfma per (n, rt) ---
#pragma unroll
    for (int n = 0; n < 4; ++n) {
      int dim = n * 16 + q15;
      bf16x8 vf[2];
#pragma unroll
      for (int c = 0; c < 2; ++c) {
        int ch = (c * 4 + g4) ^ l7;
        vf[c] = *(const bf16x8*)(lVT + dim * 128 + ch * 16);
      }
#pragma unroll
      for (int rt = 0; rt < 2; ++rt) {
        o[rt][n] = mfma16(pf[rt][0], vf[0], o[rt][n]);
        o[rt][n] = mfma16(pf[rt][1], vf[1], o[rt][n]);
      }
    }
  }

  // --- final l: reduce over the 4 g-groups of each qrow (2 shfl rounds) ---
  float lf[2];
#pragma unroll
  for (int rt = 0; rt < 2; ++rt) {
    float v = lpart[rt];
    v += __shfl_xor(v, 16, 64);
    v += __shfl_xor(v, 32, 64);
    lf[rt] = v;  // all lanes: full l for qrow=q15 of tile rt
  }

  // --- epilogue: redistribute l to D-layout rows, write AO [B,L,1024] ---
#pragma unroll
  for (int rt = 0; rt < 2; ++rt) {
    float inv[4];
#pragma unroll
    for (int r = 0; r < 4; ++r)
      inv[r] = 1.f / __shfl(lf[rt], g4 * 4 + r, 64);  // src lane g4*4+r holds that qrow's l
#pragma unroll
    for (int n = 0; n < 4; ++n) {
      int col = h * 64 + n * 16 + q15;
#pragma unroll
      for (int r = 0; r < 4; ++r) {
        int qrow = q0 + w * 32 + rt * 16 + g4 * 4 + r;
        AO[((size_t)b * L + qrow) * 1024 + col] = (bf16)(o[rt][n][r] * inv[r]);
      }
    }
  }
}

// ---------------- launch ----------------
extern "C" void kernel_launch(void* const* d_in, const int* in_sizes, int n_in,
                              void* d_out, int out_size, void* d_ws, size_t ws_size,
                              hipStream_t stream) {
  (void)in_sizes; (void)n_in; (void)out_size;
  const size_t MB = 1u << 20;
  if (ws_size < 73 * MB) return;

  const float* q  = (const float*)d_in[0];
  const float* k  = (const float*)d_in[1];
  const float* v  = (const float*)d_in[2];
  const float* Wq = (const float*)d_in[3];
  const float* bq = (const float*)d_in[4];
  const float* Wk = (const float*)d_in[5];
  const float* bk = (const float*)d_in[6];
  const float* Wv = (const float*)d_in[7];
  const float* bv = (const float*)d_in[8];
  const float* Wo = (const float*)d_in[9];
  const float* bo = (const float*)d_in[10];

  char* ws = (char*)d_ws;
  bf16* qb  = (bf16*)(ws + 0 * MB);
  bf16* kb  = (bf16*)(ws + 16 * MB);
  bf16* vb  = (bf16*)(ws + 32 * MB);
  bf16* Qa  = (bf16*)(ws + 48 * MB);
  bf16* WqT = (bf16*)(ws + 64 * MB);
  bf16* WkT = (bf16*)(ws + 66 * MB);
  bf16* WvT = (bf16*)(ws + 68 * MB);
  bf16* WoT = (bf16*)(ws + 70 * MB);
  bf16* Ka = qb;   // reuse: qb dead after Q-proj
  bf16* VTa = kb;  // reuse: kb dead after K-proj (V-proj writes VT layout here)
  bf16* AO = vb;   // reuse: vb dead after V-proj

  dim3 tb(32, 8);
  wt_cvt4_k<<<dim3(32, 32, 4), tb, 0, stream>>>(Wq, Wk, Wv, Wo, WqT, WkT, WvT, WoT);

  const int n4 = (4 * 2048 * 1024) / 4;
  cvt3_bf16_k<<<dim3(n4 / 256, 3), 256, 0, stream>>>(q, k, v, qb, kb, vb, n4);

  // Q scale folds softmax 1/8 AND 1/ln2 (exp2-based softmax; shift/scale-exact)
  gemm_k<0><<<512, 256, 0, stream>>>(qb, WqT, bq, (void*)Qa, 0.125f * 1.4426950408889634f);
  gemm_k<0><<<512, 256, 0, stream>>>(kb, WkT, bk, (void*)Ka, 1.0f);
  gemm_k<2><<<512, 256, 0, stream>>>(vb, WvT, bv, (void*)VTa, 1.0f);

  attn_mfma_k<<<1024, 256, 0, stream>>>(Qa, Ka, VTa, AO);

  gemm_k<1><<<512, 256, 0, stream>>>(AO, WoT, bo, d_out, 1.0f);
}

// Round 18
// 205.752 us; speedup vs baseline: 1.4615x; 1.0494x over previous
//
#include <hip/hip_runtime.h>
#include <hip/hip_bf16.h>
#include <stdint.h>

typedef __bf16 bf16;
typedef __bf16 bf16x8 __attribute__((ext_vector_type(8)));
typedef __bf16 bf16x4v __attribute__((ext_vector_type(4)));
typedef float f32x4 __attribute__((ext_vector_type(4)));
typedef uint32_t u32;
typedef u32 u32x2 __attribute__((ext_vector_type(2)));
typedef u32 u32x4 __attribute__((ext_vector_type(4)));

__device__ __forceinline__ void gld_lds16(const void* g, void* l) {
  __builtin_amdgcn_global_load_lds(
      (const __attribute__((address_space(1))) void*)g,
      (__attribute__((address_space(3))) void*)l, 16, 0, 0);
}

__device__ __forceinline__ f32x4 mfma16(bf16x8 a, bf16x8 b, f32x4 c) {
  return __builtin_amdgcn_mfma_f32_16x16x32_bf16(a, b, c, 0, 0, 0);
}

__device__ __forceinline__ u32 cvtpk_bf16(float lo, float hi) {
  u32 r;
  asm("v_cvt_pk_bf16_f32 %0, %1, %2" : "=v"(r) : "v"(lo), "v"(hi));
  return r;
}

__device__ __forceinline__ float fexp2(float x) {
#if __has_builtin(__builtin_amdgcn_exp2f)
  return __builtin_amdgcn_exp2f(x);
#else
  return exp2f(x);
#endif
}

// ---------------- weight fp32 [K][N] -> bf16 transposed [N][K], 4 weights fused -------
__global__ void wt_cvt4_k(const float* __restrict__ W0, const float* __restrict__ W1,
                          const float* __restrict__ W2, const float* __restrict__ W3,
                          bf16* __restrict__ T0, bf16* __restrict__ T1,
                          bf16* __restrict__ T2, bf16* __restrict__ T3) {
  const float* W = (blockIdx.z == 0) ? W0 : (blockIdx.z == 1) ? W1
                  : (blockIdx.z == 2) ? W2 : W3;
  bf16* WT = (blockIdx.z == 0) ? T0 : (blockIdx.z == 1) ? T1
            : (blockIdx.z == 2) ? T2 : T3;
  __shared__ float t[32][33];
  int tx = threadIdx.x, ty = threadIdx.y;  // 32 x 8
  int bx = blockIdx.x * 32, by = blockIdx.y * 32;
#pragma unroll
  for (int j = 0; j < 32; j += 8)
    t[ty + j][tx] = W[(size_t)(by + ty + j) * 1024 + bx + tx];
  __syncthreads();
#pragma unroll
  for (int j = 0; j < 32; j += 8)
    WT[(size_t)(bx + ty + j) * 1024 + by + tx] = (bf16)t[tx][ty + j];
}

// ---------------- FUSED QKV projection GEMM: A fp32 (converted in staging) ----------------
// blockIdx.y selects tensor: 0=Q (mode0, qscale), 1=K (mode0), 2=V (mode2 -> VT layout).
// A-staging: reg-staged fp32->bf16 with swizzled b128 writes (write chunk (l&7)^(l>>3),
// read chunk ^(lane&7) — the attn-verified involution pair). B-side: gld_lds16 (async).
__global__ __launch_bounds__(256, 2) void gemmf_k(
    const float* __restrict__ Aq, const float* __restrict__ Ak, const float* __restrict__ Av,
    const bf16* __restrict__ WTq, const bf16* __restrict__ WTk, const bf16* __restrict__ WTv,
    const float* __restrict__ bq, const float* __restrict__ bk, const float* __restrict__ bv,
    bf16* __restrict__ Qa, bf16* __restrict__ Ka, bf16* __restrict__ VTa, float qscale) {
  constexpr int K = 1024, BM = 128, BK = 64;
  constexpr int NT = K / BK;  // 16
  __shared__ char lds[2][2][BM * BK * 2];  // 64 KiB
  const int lane = threadIdx.x & 63, w = threadIdx.x >> 6;
  const int y = blockIdx.y;
  const float* A   = (y == 0) ? Aq : (y == 1) ? Ak : Av;
  const bf16* WT   = (y == 0) ? WTq : (y == 1) ? WTk : WTv;
  const float* bias = (y == 0) ? bq : (y == 1) ? bk : bv;
  const float scale = (y == 0) ? qscale : 1.0f;
  const int nwg = gridDim.x;
  int bid = (int)blockIdx.x;
  bid = (bid & 7) * (nwg >> 3) + (bid >> 3);  // XCD swizzle (512 % 8 == 0)
  const int bn = bid & 7;
  const int bm = bid >> 3;
  const int wm = (w & 1) * 64, wn = (w >> 1) * 64;
  const int l7 = lane & 7, sl = lane >> 3;
  const int sw = l7 ^ sl;  // A-write swizzled chunk (row&7 == sl)

  const char* gA = (const char*)(A + (size_t)bm * BM * K);    // fp32: row stride 4096 B
  const char* gB = (const char*)(WT + (size_t)bn * BM * K);   // bf16: row stride 2048 B

  auto stage = [&](int buf, int kt) {
    char* lA = lds[buf][0];
    char* lB = lds[buf][1];
    // B: async gld_lds16 (4 iters, linear — m97 pattern)
#pragma unroll
    for (int i = 0; i < 4; ++i) {
      int row = w * 32 + i * 8 + sl;
      size_t rb = (size_t)row * 2048 + (size_t)kt * 128 + (size_t)l7 * 16;
      gld_lds16(gB + rb, lB + (w * 32 + i * 8) * 128);
    }
    // A: reg-staged fp32 -> bf16, swizzled b128 writes (conflict-free: verified pattern)
#pragma unroll
    for (int i = 0; i < 4; ++i) {
      int row = w * 32 + i * 8 + sl;                       // row&7 == sl
      const char* src = gA + (size_t)row * 4096 + (size_t)kt * 256 + (size_t)l7 * 32;
      f32x4 a0 = *(const f32x4*)src;
      f32x4 a1 = *(const f32x4*)(src + 16);
      u32x4 pk;
      pk[0] = cvtpk_bf16(a0[0], a0[1]);
      pk[1] = cvtpk_bf16(a0[2], a0[3]);
      pk[2] = cvtpk_bf16(a1[0], a1[1]);
      pk[3] = cvtpk_bf16(a1[2], a1[3]);
      bf16x8 v8 = __builtin_bit_cast(bf16x8, pk);
      *(bf16x8*)(lA + row * 128 + sw * 16) = v8;
    }
  };

  f32x4 acc[4][4] = {};
  stage(0, 0);
  for (int kt = 0; kt < NT; ++kt) {
    __syncthreads();  // drains vm+lgkm: staged tile complete, prev tile consumed
    if (kt + 1 < NT) stage((kt + 1) & 1, kt + 1);
    const char* lA = lds[kt & 1][0];
    const char* lB = lds[kt & 1][1];
    bf16x8 af[4][2], bfr[4][2];
#pragma unroll
    for (int mi = 0; mi < 4; ++mi)
#pragma unroll
      for (int c = 0; c < 2; ++c) {
        int row = wm + mi * 16 + (lane & 15);
        int ch = (c * 4 + (lane >> 4)) ^ (lane & 7);  // inverse of the staging swizzle
        af[mi][c] = *(const bf16x8*)(lA + row * 128 + ch * 16);
      }
#pragma unroll
    for (int ni = 0; ni < 4; ++ni)
#pragma unroll
      for (int c = 0; c < 2; ++c) {
        int row = wn + ni * 16 + (lane & 15);
        int ch = c * 4 + (lane >> 4);  // B staged linear
        bfr[ni][c] = *(const bf16x8*)(lB + row * 128 + ch * 16);
      }
#pragma unroll
    for (int mi = 0; mi < 4; ++mi)
#pragma unroll
      for (int ni = 0; ni < 4; ++ni) {
        acc[mi][ni] = mfma16(af[mi][0], bfr[ni][0], acc[mi][ni]);
        acc[mi][ni] = mfma16(af[mi][1], bfr[ni][1], acc[mi][ni]);
      }
  }

#pragma unroll
  for (int ni = 0; ni < 4; ++ni) {
    int col = bn * 128 + wn + ni * 16 + (lane & 15);
    float bv2 = bias[col];
    int h = col >> 6, dh = col & 63;
    if (y != 2) {
      bf16* out = (y == 0) ? Qa : Ka;
#pragma unroll
      for (int mi = 0; mi < 4; ++mi)
#pragma unroll
        for (int r = 0; r < 4; ++r) {
          int row = bm * BM + wm + mi * 16 + (lane >> 4) * 4 + r;
          int b = row >> 11, li = row & 2047;
          out[(((size_t)(b * 16 + h) * 2048 + li) << 6) + dh] =
              (bf16)((acc[mi][ni][r] + bv2) * scale);
        }
    } else {
      bf16* out = VTa;  // VT[bh][dh][L]
#pragma unroll
      for (int mi = 0; mi < 4; ++mi)
#pragma unroll
        for (int r = 0; r < 4; ++r) {
          int row = bm * BM + wm + mi * 16 + (lane >> 4) * 4 + r;
          int b = row >> 11, li = row & 2047;
          out[(((size_t)(b * 16 + h) * 64 + dh) << 11) + li] =
              (bf16)(acc[mi][ni][r] + bv2);
        }
    }
  }
}

// ---------------- out-projection GEMM (bf16 A via gld_lds16, fp32 out) ----------------
__global__ __launch_bounds__(256, 2) void gemm_out_k(
    const bf16* __restrict__ A, const bf16* __restrict__ WT,
    const float* __restrict__ bias, float* __restrict__ Cout) {
  constexpr int K = 1024, N = 1024, BM = 128, BK = 64;
  constexpr int NT = K / BK;  // 16
  __shared__ char lds[2][2][BM * BK * 2];
  const int lane = threadIdx.x & 63, w = threadIdx.x >> 6;
  const int nwg = gridDim.x;
  int bid = (int)blockIdx.x;
  bid = (bid & 7) * (nwg >> 3) + (bid >> 3);
  const int bn = bid & 7;
  const int bm = bid >> 3;
  const int wm = (w & 1) * 64, wn = (w >> 1) * 64;

  const char* gA = (const char*)(A + (size_t)bm * BM * K);
  const char* gB = (const char*)(WT + (size_t)bn * BM * K);

  auto stage = [&](int buf, int kt) {
    char* lA = lds[buf][0];
    char* lB = lds[buf][1];
#pragma unroll
    for (int i = 0; i < 4; ++i) {
      int row = w * 32 + i * 8 + (lane >> 3);
      size_t rb = (size_t)row * (K * 2) + (size_t)kt * (BK * 2) + (size_t)(lane & 7) * 16;
      gld_lds16(gA + rb, lA + (w * 32 + i * 8) * 128);
      gld_lds16(gB + rb, lB + (w * 32 + i * 8) * 128);
    }
  };

  f32x4 acc[4][4] = {};
  stage(0, 0);
  for (int kt = 0; kt < NT; ++kt) {
    __syncthreads();
    if (kt + 1 < NT) stage((kt + 1) & 1, kt + 1);
    const char* lA = lds[kt & 1][0];
    const char* lB = lds[kt & 1][1];
    bf16x8 af[4][2], bfr[4][2];
#pragma unroll
    for (int mi = 0; mi < 4; ++mi)
#pragma unroll
      for (int c = 0; c < 2; ++c) {
        int row = wm + mi * 16 + (lane & 15);
        int ch = c * 4 + (lane >> 4);
        af[mi][c] = *(const bf16x8*)(lA + row * 128 + ch * 16);
      }
#pragma unroll
    for (int ni = 0; ni < 4; ++ni)
#pragma unroll
      for (int c = 0; c < 2; ++c) {
        int row = wn + ni * 16 + (lane & 15);
        int ch = c * 4 + (lane >> 4);
        bfr[ni][c] = *(const bf16x8*)(lB + row * 128 + ch * 16);
      }
#pragma unroll
    for (int mi = 0; mi < 4; ++mi)
#pragma unroll
      for (int ni = 0; ni < 4; ++ni) {
        acc[mi][ni] = mfma16(af[mi][0], bfr[ni][0], acc[mi][ni]);
        acc[mi][ni] = mfma16(af[mi][1], bfr[ni][1], acc[mi][ni]);
      }
  }

#pragma unroll
  for (int ni = 0; ni < 4; ++ni) {
    int col = bn * 128 + wn + ni * 16 + (lane & 15);
    float bv = bias[col];
#pragma unroll
    for (int mi = 0; mi < 4; ++mi)
#pragma unroll
      for (int r = 0; r < 4; ++r) {
        int row = bm * BM + wm + mi * 16 + (lane >> 4) * 4 + r;
        Cout[(size_t)row * N + col] = acc[mi][ni][r] + bv;
      }
  }
}

// ---------------- MFMA flash attention v7 (r17, unchanged: 98 us, passing) ----------------
__global__ __launch_bounds__(256, 3) void attn_mfma_k(
    const bf16* __restrict__ Q, const bf16* __restrict__ Kg,
    const bf16* __restrict__ VT, bf16* __restrict__ AO) {
  constexpr int L = 2048, DH = 64, NT = L / 64;
  __shared__ char ldsK[2][8192];
  __shared__ char ldsVT[2][8192];
  __shared__ char ldsP[4][2][2048];
  const int lane = threadIdx.x & 63, w = threadIdx.x >> 6;
  const int nwg = gridDim.x;
  int bid = (int)blockIdx.x;
  bid = (bid & 7) * (nwg >> 3) + (bid >> 3);
  const int bh = bid >> 4;
  const int q0 = (bid & 15) * 128;
  const int b = bh >> 4, h = bh & 15;
  const int l7 = lane & 7;
  const int q15 = lane & 15, g4 = lane >> 4;
  const int sl = lane >> 3;
  const int sw = l7 ^ sl;

  const bf16* Qbase = Q + ((size_t)bh * L + q0 + w * 32) * DH;
  bf16x8 qf[2][2];
#pragma unroll
  for (int rt = 0; rt < 2; ++rt)
#pragma unroll
    for (int c = 0; c < 2; ++c)
      qf[rt][c] = *(const bf16x8*)(Qbase + (size_t)(rt * 16 + q15) * DH +
                                   (c * 4 + g4) * 8);

  const char* Kp  = (const char*)(Kg + (size_t)bh * L * DH);
  const char* VTp = (const char*)(VT + (size_t)bh * DH * L);

  auto stage = [&](int buf, int kt) {
#pragma unroll
    for (int c = 0; c < 2; ++c) {
      int chunk = w * 2 + c;
      int row = chunk * 8 + sl;
      gld_lds16(Kp + (size_t)kt * 8192 + (size_t)row * 128 + sw * 16,
                ldsK[buf] + chunk * 1024);
      gld_lds16(VTp + (size_t)row * 4096 + (size_t)kt * 128 + sw * 16,
                ldsVT[buf] + chunk * 1024);
    }
  };

  f32x4 o[2][4] = {};
  float lpart[2] = {0.f, 0.f};

  stage(0, 0);
  for (int kt = 0; kt < NT; ++kt) {
    __syncthreads();
    if (kt + 1 < NT) stage((kt + 1) & 1, kt + 1);
    const char* lK  = ldsK[kt & 1];
    const char* lVT = ldsVT[kt & 1];

    bf16x8 kf[4][2];
#pragma unroll
    for (int sub = 0; sub < 4; ++sub)
#pragma unroll
      for (int c = 0; c < 2; ++c) {
        int key = sub * 16 + q15;
        int ch = (c * 4 + g4) ^ l7;
        kf[sub][c] = *(const bf16x8*)(lK + key * 128 + ch * 16);
      }

#pragma unroll
    for (int rt = 0; rt < 2; ++rt) {
      f32x4 s[4];
#pragma unroll
      for (int sub = 0; sub < 4; ++sub) {
        f32x4 acc = {};
        acc = mfma16(kf[sub][0], qf[rt][0], acc);
        acc = mfma16(kf[sub][1], qf[rt][1], acc);
        s[sub] = acc;
      }
#pragma unroll
      for (int sub = 0; sub < 4; ++sub) {
        float p0 = fexp2(s[sub][0]), p1 = fexp2(s[sub][1]);
        float p2 = fexp2(s[sub][2]), p3 = fexp2(s[sub][3]);
        lpart[rt] += (p0 + p1) + (p2 + p3);
        u32x2 pw;
        pw[0] = cvtpk_bf16(p0, p1);
        pw[1] = cvtpk_bf16(p2, p3);
        bf16x4v pv = __builtin_bit_cast(bf16x4v, pw);
        int chs = (2 * sub + (g4 >> 1)) ^ l7;
        *(bf16x4v*)(ldsP[w][rt] + q15 * 128 + chs * 16 + (g4 & 1) * 8) = pv;
      }
    }

    asm volatile("s_waitcnt lgkmcnt(0)" ::: "memory");
    __builtin_amdgcn_sched_barrier(0);

    bf16x8 pf[2][2];
#pragma unroll
    for (int rt = 0; rt < 2; ++rt)
#pragma unroll
      for (int c = 0; c < 2; ++c) {
        int ch = (c * 4 + g4) ^ l7;
        pf[rt][c] = *(const bf16x8*)(ldsP[w][rt] + q15 * 128 + ch * 16);
      }

#pragma unroll
    for (int n = 0; n < 4; ++n) {
      int dim = n * 16 + q15;
      bf16x8 vf[2];
#pragma unroll
      for (int c = 0; c < 2; ++c) {
        int ch = (c * 4 + g4) ^ l7;
        vf[c] = *(const bf16x8*)(lVT + dim * 128 + ch * 16);
      }
#pragma unroll
      for (int rt = 0; rt < 2; ++rt) {
        o[rt][n] = mfma16(pf[rt][0], vf[0], o[rt][n]);
        o[rt][n] = mfma16(pf[rt][1], vf[1], o[rt][n]);
      }
    }
  }

  float lf[2];
#pragma unroll
  for (int rt = 0; rt < 2; ++rt) {
    float v = lpart[rt];
    v += __shfl_xor(v, 16, 64);
    v += __shfl_xor(v, 32, 64);
    lf[rt] = v;
  }

#pragma unroll
  for (int rt = 0; rt < 2; ++rt) {
    float inv[4];
#pragma unroll
    for (int r = 0; r < 4; ++r)
      inv[r] = 1.f / __shfl(lf[rt], g4 * 4 + r, 64);
#pragma unroll
    for (int n = 0; n < 4; ++n) {
      int col = h * 64 + n * 16 + q15;
#pragma unroll
      for (int r = 0; r < 4; ++r) {
        int qrow = q0 + w * 32 + rt * 16 + g4 * 4 + r;
        AO[((size_t)b * L + qrow) * 1024 + col] = (bf16)(o[rt][n][r] * inv[r]);
      }
    }
  }
}

// ---------------- launch ----------------
extern "C" void kernel_launch(void* const* d_in, const int* in_sizes, int n_in,
                              void* d_out, int out_size, void* d_ws, size_t ws_size,
                              hipStream_t stream) {
  (void)in_sizes; (void)n_in; (void)out_size;
  const size_t MB = 1u << 20;
  if (ws_size < 73 * MB) return;

  const float* q  = (const float*)d_in[0];
  const float* k  = (const float*)d_in[1];
  const float* v  = (const float*)d_in[2];
  const float* Wq = (const float*)d_in[3];
  const float* bq = (const float*)d_in[4];
  const float* Wk = (const float*)d_in[5];
  const float* bk = (const float*)d_in[6];
  const float* Wv = (const float*)d_in[7];
  const float* bv = (const float*)d_in[8];
  const float* Wo = (const float*)d_in[9];
  const float* bo = (const float*)d_in[10];

  char* ws = (char*)d_ws;
  bf16* Qa  = (bf16*)(ws + 0 * MB);    // 16 MB
  bf16* Ka  = (bf16*)(ws + 16 * MB);   // 16 MB
  bf16* VTa = (bf16*)(ws + 32 * MB);   // 16 MB
  bf16* AO  = (bf16*)(ws + 48 * MB);   // 16 MB
  bf16* WqT = (bf16*)(ws + 64 * MB);
  bf16* WkT = (bf16*)(ws + 66 * MB);
  bf16* WvT = (bf16*)(ws + 68 * MB);
  bf16* WoT = (bf16*)(ws + 70 * MB);

  dim3 tb(32, 8);
  wt_cvt4_k<<<dim3(32, 32, 4), tb, 0, stream>>>(Wq, Wk, Wv, Wo, WqT, WkT, WvT, WoT);

  // fused fp32->bf16 QKV projections (one dispatch, 512x3 blocks)
  // Q scale folds softmax 1/8 AND 1/ln2 (exp2-based softmax)
  gemmf_k<<<dim3(512, 3), 256, 0, stream>>>(
      q, k, v, WqT, WkT, WvT, bq, bk, bv, Qa, Ka, VTa,
      0.125f * 1.4426950408889634f);

  attn_mfma_k<<<1024, 256, 0, stream>>>(Qa, Ka, VTa, AO);

  gemm_out_k<<<512, 256, 0, stream>>>(AO, WoT, bo, (float*)d_out);
}

// Round 19
// 202.321 us; speedup vs baseline: 1.4863x; 1.0170x over previous
//
#include <hip/hip_runtime.h>
#include <hip/hip_bf16.h>
#include <stdint.h>

typedef __bf16 bf16;
typedef __bf16 bf16x8 __attribute__((ext_vector_type(8)));
typedef __bf16 bf16x4v __attribute__((ext_vector_type(4)));
typedef float f32x4 __attribute__((ext_vector_type(4)));
typedef uint32_t u32;
typedef u32 u32x2 __attribute__((ext_vector_type(2)));
typedef u32 u32x4 __attribute__((ext_vector_type(4)));

__device__ __forceinline__ void gld_lds16(const void* g, void* l) {
  __builtin_amdgcn_global_load_lds(
      (const __attribute__((address_space(1))) void*)g,
      (__attribute__((address_space(3))) void*)l, 16, 0, 0);
}

__device__ __forceinline__ f32x4 mfma16(bf16x8 a, bf16x8 b, f32x4 c) {
  return __builtin_amdgcn_mfma_f32_16x16x32_bf16(a, b, c, 0, 0, 0);
}

__device__ __forceinline__ u32 cvtpk_bf16(float lo, float hi) {
  u32 r;
  asm("v_cvt_pk_bf16_f32 %0, %1, %2" : "=v"(r) : "v"(lo), "v"(hi));
  return r;
}

__device__ __forceinline__ float fexp2(float x) {
#if __has_builtin(__builtin_amdgcn_exp2f)
  return __builtin_amdgcn_exp2f(x);
#else
  return exp2f(x);
#endif
}

// ---------------- weight fp32 [K][N] -> bf16 transposed [N][K], 4 weights fused -------
__global__ void wt_cvt4_k(const float* __restrict__ W0, const float* __restrict__ W1,
                          const float* __restrict__ W2, const float* __restrict__ W3,
                          bf16* __restrict__ T0, bf16* __restrict__ T1,
                          bf16* __restrict__ T2, bf16* __restrict__ T3) {
  const float* W = (blockIdx.z == 0) ? W0 : (blockIdx.z == 1) ? W1
                  : (blockIdx.z == 2) ? W2 : W3;
  bf16* WT = (blockIdx.z == 0) ? T0 : (blockIdx.z == 1) ? T1
            : (blockIdx.z == 2) ? T2 : T3;
  __shared__ float t[32][33];
  int tx = threadIdx.x, ty = threadIdx.y;  // 32 x 8
  int bx = blockIdx.x * 32, by = blockIdx.y * 32;
#pragma unroll
  for (int j = 0; j < 32; j += 8)
    t[ty + j][tx] = W[(size_t)(by + ty + j) * 1024 + bx + tx];
  __syncthreads();
#pragma unroll
  for (int j = 0; j < 32; j += 8)
    WT[(size_t)(bx + ty + j) * 1024 + by + tx] = (bf16)t[tx][ty + j];
}

// ---------------- FUSED QKV projection GEMM: A fp32, T14 async-STAGE split ----------------
// blockIdx.y selects: 0=Q (mode0, qscale), 1=K (mode0), 2=V (mode2 -> VT layout).
// A-path split: stage_loadA (issue fp32 loads -> regs, right after barrier) ...
// MFMA compute ... stage_writeA (cvt_pk + swizzled ds_write) — HBM latency hides
// under the 32-MFMA phase instead of blocking before it (r18 regression cause).
__global__ __launch_bounds__(256, 2) void gemmf_k(
    const float* __restrict__ Aq, const float* __restrict__ Ak, const float* __restrict__ Av,
    const bf16* __restrict__ WTq, const bf16* __restrict__ WTk, const bf16* __restrict__ WTv,
    const float* __restrict__ bq, const float* __restrict__ bk, const float* __restrict__ bv,
    bf16* __restrict__ Qa, bf16* __restrict__ Ka, bf16* __restrict__ VTa, float qscale) {
  constexpr int K = 1024, BM = 128, BK = 64;
  constexpr int NT = K / BK;  // 16
  __shared__ char lds[2][2][BM * BK * 2];  // 64 KiB
  const int lane = threadIdx.x & 63, w = threadIdx.x >> 6;
  const int y = blockIdx.y;
  const float* A   = (y == 0) ? Aq : (y == 1) ? Ak : Av;
  const bf16* WT   = (y == 0) ? WTq : (y == 1) ? WTk : WTv;
  const float* bias = (y == 0) ? bq : (y == 1) ? bk : bv;
  const float scale = (y == 0) ? qscale : 1.0f;
  const int nwg = gridDim.x;
  int bid = (int)blockIdx.x;
  bid = (bid & 7) * (nwg >> 3) + (bid >> 3);  // XCD swizzle (512 % 8 == 0)
  const int bn = bid & 7;
  const int bm = bid >> 3;
  const int wm = (w & 1) * 64, wn = (w >> 1) * 64;
  const int l7 = lane & 7, sl = lane >> 3;
  const int sw = l7 ^ sl;  // A-write swizzled chunk (row&7 == sl)

  const char* gA = (const char*)(A + (size_t)bm * BM * K);    // fp32: row stride 4096 B
  const char* gB = (const char*)(WT + (size_t)bn * BM * K);   // bf16: row stride 2048 B

  auto stageB = [&](int buf, int kt) {
    char* lB = lds[buf][1];
#pragma unroll
    for (int i = 0; i < 4; ++i) {
      int row = w * 32 + i * 8 + sl;
      gld_lds16(gB + (size_t)row * 2048 + (size_t)kt * 128 + (size_t)l7 * 16,
                lB + (w * 32 + i * 8) * 128);
    }
  };
  auto stage_loadA = [&](int kt, f32x4 (&a0)[4], f32x4 (&a1)[4]) {
#pragma unroll
    for (int i = 0; i < 4; ++i) {
      int row = w * 32 + i * 8 + sl;
      const char* src = gA + (size_t)row * 4096 + (size_t)kt * 256 + (size_t)l7 * 32;
      a0[i] = *(const f32x4*)src;
      a1[i] = *(const f32x4*)(src + 16);
    }
  };
  auto stage_writeA = [&](int buf, f32x4 (&a0)[4], f32x4 (&a1)[4]) {
    char* lA = lds[buf][0];
#pragma unroll
    for (int i = 0; i < 4; ++i) {
      int row = w * 32 + i * 8 + sl;
      u32x4 pk;
      pk[0] = cvtpk_bf16(a0[i][0], a0[i][1]);
      pk[1] = cvtpk_bf16(a0[i][2], a0[i][3]);
      pk[2] = cvtpk_bf16(a1[i][0], a1[i][1]);
      pk[3] = cvtpk_bf16(a1[i][2], a1[i][3]);
      *(bf16x8*)(lA + row * 128 + sw * 16) = __builtin_bit_cast(bf16x8, pk);
    }
  };

  f32x4 a0[4], a1[4];
  // prologue: tile 0 staged synchronously
  stageB(0, 0);
  stage_loadA(0, a0, a1);
  stage_writeA(0, a0, a1);

  f32x4 acc[4][4] = {};
  for (int kt = 0; kt < NT; ++kt) {
    __syncthreads();  // tile kt fully staged (vm+lgkm drained); prev tile consumed
    if (kt + 1 < NT) {
      stageB((kt + 1) & 1, kt + 1);       // async into LDS (vmcnt)
      stage_loadA(kt + 1, a0, a1);        // issue loads; consumed AFTER compute
    }
    const char* lA = lds[kt & 1][0];
    const char* lB = lds[kt & 1][1];
    bf16x8 af[4][2], bfr[4][2];
#pragma unroll
    for (int mi = 0; mi < 4; ++mi)
#pragma unroll
      for (int c = 0; c < 2; ++c) {
        int row = wm + mi * 16 + (lane & 15);
        int ch = (c * 4 + (lane >> 4)) ^ (lane & 7);  // inverse of the staging swizzle
        af[mi][c] = *(const bf16x8*)(lA + row * 128 + ch * 16);
      }
#pragma unroll
    for (int ni = 0; ni < 4; ++ni)
#pragma unroll
      for (int c = 0; c < 2; ++c) {
        int row = wn + ni * 16 + (lane & 15);
        int ch = c * 4 + (lane >> 4);  // B staged linear
        bfr[ni][c] = *(const bf16x8*)(lB + row * 128 + ch * 16);
      }
#pragma unroll
    for (int mi = 0; mi < 4; ++mi)
#pragma unroll
      for (int ni = 0; ni < 4; ++ni) {
        acc[mi][ni] = mfma16(af[mi][0], bfr[ni][0], acc[mi][ni]);
        acc[mi][ni] = mfma16(af[mi][1], bfr[ni][1], acc[mi][ni]);
      }
    if (kt + 1 < NT) stage_writeA((kt + 1) & 1, a0, a1);  // cvt+write after compute
  }

#pragma unroll
  for (int ni = 0; ni < 4; ++ni) {
    int col = bn * 128 + wn + ni * 16 + (lane & 15);
    float bv2 = bias[col];
    int h = col >> 6, dh = col & 63;
    if (y != 2) {
      bf16* out = (y == 0) ? Qa : Ka;
#pragma unroll
      for (int mi = 0; mi < 4; ++mi)
#pragma unroll
        for (int r = 0; r < 4; ++r) {
          int row = bm * BM + wm + mi * 16 + (lane >> 4) * 4 + r;
          int b = row >> 11, li = row & 2047;
          out[(((size_t)(b * 16 + h) * 2048 + li) << 6) + dh] =
              (bf16)((acc[mi][ni][r] + bv2) * scale);
        }
    } else {
      bf16* out = VTa;  // VT[bh][dh][L]
#pragma unroll
      for (int mi = 0; mi < 4; ++mi)
#pragma unroll
        for (int r = 0; r < 4; ++r) {
          int row = bm * BM + wm + mi * 16 + (lane >> 4) * 4 + r;
          int b = row >> 11, li = row & 2047;
          out[(((size_t)(b * 16 + h) * 64 + dh) << 11) + li] =
              (bf16)(acc[mi][ni][r] + bv2);
        }
    }
  }
}

// ---------------- out-projection GEMM (bf16 A via gld_lds16, fp32 out) ----------------
__global__ __launch_bounds__(256, 2) void gemm_out_k(
    const bf16* __restrict__ A, const bf16* __restrict__ WT,
    const float* __restrict__ bias, float* __restrict__ Cout) {
  constexpr int K = 1024, N = 1024, BM = 128, BK = 64;
  constexpr int NT = K / BK;  // 16
  __shared__ char lds[2][2][BM * BK * 2];
  const int lane = threadIdx.x & 63, w = threadIdx.x >> 6;
  const int nwg = gridDim.x;
  int bid = (int)blockIdx.x;
  bid = (bid & 7) * (nwg >> 3) + (bid >> 3);
  const int bn = bid & 7;
  const int bm = bid >> 3;
  const int wm = (w & 1) * 64, wn = (w >> 1) * 64;

  const char* gA = (const char*)(A + (size_t)bm * BM * K);
  const char* gB = (const char*)(WT + (size_t)bn * BM * K);

  auto stage = [&](int buf, int kt) {
    char* lA = lds[buf][0];
    char* lB = lds[buf][1];
#pragma unroll
    for (int i = 0; i < 4; ++i) {
      int row = w * 32 + i * 8 + (lane >> 3);
      size_t rb = (size_t)row * (K * 2) + (size_t)kt * (BK * 2) + (size_t)(lane & 7) * 16;
      gld_lds16(gA + rb, lA + (w * 32 + i * 8) * 128);
      gld_lds16(gB + rb, lB + (w * 32 + i * 8) * 128);
    }
  };

  f32x4 acc[4][4] = {};
  stage(0, 0);
  for (int kt = 0; kt < NT; ++kt) {
    __syncthreads();
    if (kt + 1 < NT) stage((kt + 1) & 1, kt + 1);
    const char* lA = lds[kt & 1][0];
    const char* lB = lds[kt & 1][1];
    bf16x8 af[4][2], bfr[4][2];
#pragma unroll
    for (int mi = 0; mi < 4; ++mi)
#pragma unroll
      for (int c = 0; c < 2; ++c) {
        int row = wm + mi * 16 + (lane & 15);
        int ch = c * 4 + (lane >> 4);
        af[mi][c] = *(const bf16x8*)(lA + row * 128 + ch * 16);
      }
#pragma unroll
    for (int ni = 0; ni < 4; ++ni)
#pragma unroll
      for (int c = 0; c < 2; ++c) {
        int row = wn + ni * 16 + (lane & 15);
        int ch = c * 4 + (lane >> 4);
        bfr[ni][c] = *(const bf16x8*)(lB + row * 128 + ch * 16);
      }
#pragma unroll
    for (int mi = 0; mi < 4; ++mi)
#pragma unroll
      for (int ni = 0; ni < 4; ++ni) {
        acc[mi][ni] = mfma16(af[mi][0], bfr[ni][0], acc[mi][ni]);
        acc[mi][ni] = mfma16(af[mi][1], bfr[ni][1], acc[mi][ni]);
      }
  }

#pragma unroll
  for (int ni = 0; ni < 4; ++ni) {
    int col = bn * 128 + wn + ni * 16 + (lane & 15);
    float bv = bias[col];
#pragma unroll
    for (int mi = 0; mi < 4; ++mi)
#pragma unroll
      for (int r = 0; r < 4; ++r) {
        int row = bm * BM + wm + mi * 16 + (lane >> 4) * 4 + r;
        Cout[(size_t)row * N + col] = acc[mi][ni][r] + bv;
      }
  }
}

// ---------------- MFMA flash attention v7 (r17, unchanged: 98 us, passing) ----------------
__global__ __launch_bounds__(256, 3) void attn_mfma_k(
    const bf16* __restrict__ Q, const bf16* __restrict__ Kg,
    const bf16* __restrict__ VT, bf16* __restrict__ AO) {
  constexpr int L = 2048, DH = 64, NT = L / 64;
  __shared__ char ldsK[2][8192];
  __shared__ char ldsVT[2][8192];
  __shared__ char ldsP[4][2][2048];
  const int lane = threadIdx.x & 63, w = threadIdx.x >> 6;
  const int nwg = gridDim.x;
  int bid = (int)blockIdx.x;
  bid = (bid & 7) * (nwg >> 3) + (bid >> 3);
  const int bh = bid >> 4;
  const int q0 = (bid & 15) * 128;
  const int b = bh >> 4, h = bh & 15;
  const int l7 = lane & 7;
  const int q15 = lane & 15, g4 = lane >> 4;
  const int sl = lane >> 3;
  const int sw = l7 ^ sl;

  const bf16* Qbase = Q + ((size_t)bh * L + q0 + w * 32) * DH;
  bf16x8 qf[2][2];
#pragma unroll
  for (int rt = 0; rt < 2; ++rt)
#pragma unroll
    for (int c = 0; c < 2; ++c)
      qf[rt][c] = *(const bf16x8*)(Qbase + (size_t)(rt * 16 + q15) * DH +
                                   (c * 4 + g4) * 8);

  const char* Kp  = (const char*)(Kg + (size_t)bh * L * DH);
  const char* VTp = (const char*)(VT + (size_t)bh * DH * L);

  auto stage = [&](int buf, int kt) {
#pragma unroll
    for (int c = 0; c < 2; ++c) {
      int chunk = w * 2 + c;
      int row = chunk * 8 + sl;
      gld_lds16(Kp + (size_t)kt * 8192 + (size_t)row * 128 + sw * 16,
                ldsK[buf] + chunk * 1024);
      gld_lds16(VTp + (size_t)row * 4096 + (size_t)kt * 128 + sw * 16,
                ldsVT[buf] + chunk * 1024);
    }
  };

  f32x4 o[2][4] = {};
  float lpart[2] = {0.f, 0.f};

  stage(0, 0);
  for (int kt = 0; kt < NT; ++kt) {
    __syncthreads();
    if (kt + 1 < NT) stage((kt + 1) & 1, kt + 1);
    const char* lK  = ldsK[kt & 1];
    const char* lVT = ldsVT[kt & 1];

    bf16x8 kf[4][2];
#pragma unroll
    for (int sub = 0; sub < 4; ++sub)
#pragma unroll
      for (int c = 0; c < 2; ++c) {
        int key = sub * 16 + q15;
        int ch = (c * 4 + g4) ^ l7;
        kf[sub][c] = *(const bf16x8*)(lK + key * 128 + ch * 16);
      }

#pragma unroll
    for (int rt = 0; rt < 2; ++rt) {
      f32x4 s[4];
#pragma unroll
      for (int sub = 0; sub < 4; ++sub) {
        f32x4 acc = {};
        acc = mfma16(kf[sub][0], qf[rt][0], acc);
        acc = mfma16(kf[sub][1], qf[rt][1], acc);
        s[sub] = acc;
      }
#pragma unroll
      for (int sub = 0; sub < 4; ++sub) {
        float p0 = fexp2(s[sub][0]), p1 = fexp2(s[sub][1]);
        float p2 = fexp2(s[sub][2]), p3 = fexp2(s[sub][3]);
        lpart[rt] += (p0 + p1) + (p2 + p3);
        u32x2 pw;
        pw[0] = cvtpk_bf16(p0, p1);
        pw[1] = cvtpk_bf16(p2, p3);
        bf16x4v pv = __builtin_bit_cast(bf16x4v, pw);
        int chs = (2 * sub + (g4 >> 1)) ^ l7;
        *(bf16x4v*)(ldsP[w][rt] + q15 * 128 + chs * 16 + (g4 & 1) * 8) = pv;
      }
    }

    asm volatile("s_waitcnt lgkmcnt(0)" ::: "memory");
    __builtin_amdgcn_sched_barrier(0);

    bf16x8 pf[2][2];
#pragma unroll
    for (int rt = 0; rt < 2; ++rt)
#pragma unroll
      for (int c = 0; c < 2; ++c) {
        int ch = (c * 4 + g4) ^ l7;
        pf[rt][c] = *(const bf16x8*)(ldsP[w][rt] + q15 * 128 + ch * 16);
      }

#pragma unroll
    for (int n = 0; n < 4; ++n) {
      int dim = n * 16 + q15;
      bf16x8 vf[2];
#pragma unroll
      for (int c = 0; c < 2; ++c) {
        int ch = (c * 4 + g4) ^ l7;
        vf[c] = *(const bf16x8*)(lVT + dim * 128 + ch * 16);
      }
#pragma unroll
      for (int rt = 0; rt < 2; ++rt) {
        o[rt][n] = mfma16(pf[rt][0], vf[0], o[rt][n]);
        o[rt][n] = mfma16(pf[rt][1], vf[1], o[rt][n]);
      }
    }
  }

  float lf[2];
#pragma unroll
  for (int rt = 0; rt < 2; ++rt) {
    float v = lpart[rt];
    v += __shfl_xor(v, 16, 64);
    v += __shfl_xor(v, 32, 64);
    lf[rt] = v;
  }

#pragma unroll
  for (int rt = 0; rt < 2; ++rt) {
    float inv[4];
#pragma unroll
    for (int r = 0; r < 4; ++r)
      inv[r] = 1.f / __shfl(lf[rt], g4 * 4 + r, 64);
#pragma unroll
    for (int n = 0; n < 4; ++n) {
      int col = h * 64 + n * 16 + q15;
#pragma unroll
      for (int r = 0; r < 4; ++r) {
        int qrow = q0 + w * 32 + rt * 16 + g4 * 4 + r;
        AO[((size_t)b * L + qrow) * 1024 + col] = (bf16)(o[rt][n][r] * inv[r]);
      }
    }
  }
}

// ---------------- launch ----------------
extern "C" void kernel_launch(void* const* d_in, const int* in_sizes, int n_in,
                              void* d_out, int out_size, void* d_ws, size_t ws_size,
                              hipStream_t stream) {
  (void)in_sizes; (void)n_in; (void)out_size;
  const size_t MB = 1u << 20;
  if (ws_size < 73 * MB) return;

  const float* q  = (const float*)d_in[0];
  const float* k  = (const float*)d_in[1];
  const float* v  = (const float*)d_in[2];
  const float* Wq = (const float*)d_in[3];
  const float* bq = (const float*)d_in[4];
  const float* Wk = (const float*)d_in[5];
  const float* bk = (const float*)d_in[6];
  const float* Wv = (const float*)d_in[7];
  const float* bv = (const float*)d_in[8];
  const float* Wo = (const float*)d_in[9];
  const float* bo = (const float*)d_in[10];

  char* ws = (char*)d_ws;
  bf16* Qa  = (bf16*)(ws + 0 * MB);    // 16 MB
  bf16* Ka  = (bf16*)(ws + 16 * MB);   // 16 MB
  bf16* VTa = (bf16*)(ws + 32 * MB);   // 16 MB
  bf16* AO  = (bf16*)(ws + 48 * MB);   // 16 MB
  bf16* WqT = (bf16*)(ws + 64 * MB);
  bf16* WkT = (bf16*)(ws + 66 * MB);
  bf16* WvT = (bf16*)(ws + 68 * MB);
  bf16* WoT = (bf16*)(ws + 70 * MB);

  dim3 tb(32, 8);
  wt_cvt4_k<<<dim3(32, 32, 4), tb, 0, stream>>>(Wq, Wk, Wv, Wo, WqT, WkT, WvT, WoT);

  // fused fp32->bf16 QKV projections (one dispatch, 512x3 blocks)
  // Q scale folds softmax 1/8 AND 1/ln2 (exp2-based softmax)
  gemmf_k<<<dim3(512, 3), 256, 0, stream>>>(
      q, k, v, WqT, WkT, WvT, bq, bk, bv, Qa, Ka, VTa,
      0.125f * 1.4426950408889634f);

  attn_mfma_k<<<1024, 256, 0, stream>>>(Qa, Ka, VTa, AO);

  gemm_out_k<<<512, 256, 0, stream>>>(AO, WoT, bo, (float*)d_out);
}